// Round 13
// baseline (104.364 us; speedup 1.0000x reference)
//
#include <hip/hip_runtime.h>
#include <stdint.h>

#define NB 32
#define NQ 2048
#define NKK 2048
#define DH 128

constexpr int QBLK = 128;
constexpr int KBLK = 64;
constexpr int NKT  = NKK / KBLK;            // 32
constexpr float C2 = 0.12754299817f;        // log2(e)/sqrt(128)

typedef short short8  __attribute__((ext_vector_type(8)));
typedef float f32x4   __attribute__((ext_vector_type(4)));
typedef float f32x16  __attribute__((ext_vector_type(16)));
typedef uint32_t u32x4 __attribute__((ext_vector_type(4)));

typedef __attribute__((address_space(3))) uint32_t lds_u32_t;
typedef __attribute__((address_space(1))) const uint32_t glb_u32_t;

__device__ __forceinline__ uint16_t f2bf(float x) {
    union { float f; uint32_t u; } v; v.f = x;
    uint32_t r = v.u + 0x7fffu + ((v.u >> 16) & 1u);   // RNE
    return (uint16_t)(r >> 16);
}

__device__ __forceinline__ void gload16(const void* g, void* l) {
    __builtin_amdgcn_global_load_lds((glb_u32_t*)g, (lds_u32_t*)l, 16, 0, 0);
}

__device__ __forceinline__ uint32_t cvtpk(float lo, float hi) {
    uint32_t d;
    asm("v_cvt_pk_bf16_f32 %0, %1, %2" : "=v"(d) : "v"(lo), "v"(hi));
    return d;
}

// ---------------- prep 1: K[b][k][d] fp32 -> Kf fragment stream (verbatim r5) ----------------
// Tile (b,kt) -> 16 segs x 64 lanes x 16B. Seg s = ci*8+t: lane l = (hh<<5)|mm holds
// bf16 K[kt*64 + ci*32 + mm][t*16 + hh*8 + 0..7]  (A-frag of mfma_32x32x16, keys=rows)
__global__ void conv_kf(const float* __restrict__ K, uint16_t* __restrict__ Kf) {
    __shared__ __align__(16) uint16_t T[64][136];
    const int bid = blockIdx.x;             // b*32 + kt
    const int b = bid >> 5, kt = bid & 31;
    const int tid = threadIdx.x;
    const float* src = K + ((size_t)(b * NKK + kt * 64)) * DH;
    #pragma unroll
    for (int r = 0; r < 8; ++r) {
        int flat = r * 256 + tid;           // 2048 f32x4 chunks
        int row = flat >> 5;
        int c4 = (flat & 31) * 4;
        f32x4 x = *(const f32x4*)(src + (size_t)row * DH + c4);
        T[row][c4 + 0] = f2bf(x[0]);
        T[row][c4 + 1] = f2bf(x[1]);
        T[row][c4 + 2] = f2bf(x[2]);
        T[row][c4 + 3] = f2bf(x[3]);
    }
    __syncthreads();
    uint16_t* dst = Kf + (size_t)bid * 8192;
    #pragma unroll
    for (int r = 0; r < 4; ++r) {
        int c = r * 256 + tid;              // chunk 0..1023
        int s = c >> 6, lane = c & 63;
        int ci = s >> 3, t = s & 7;
        int mm = lane & 31, hh = lane >> 5;
        short8 v = *(const short8*)&T[ci * 32 + mm][t * 16 + hh * 8];
        *(short8*)(dst + (size_t)c * 8) = v;
    }
}

// ---------------- prep 2: V[b][k][d] fp32 -> Vf fragment stream (verbatim r5) ----------------
// Seg s = ci*8 + nt*2 + uu: lane l=(h<<5)|m holds bf16
// V[kt*64 + ci*32 + uu*16 + 4h + (j&3)+8*(j>>2)][nt*32 + m], j=0..7  (B-frag of PV)
__global__ void conv_vf(const float* __restrict__ V, uint16_t* __restrict__ Vf) {
    const int bid = blockIdx.x;             // b*32 + kt
    const int b = bid >> 5, kt = bid & 31;
    const int tid = threadIdx.x;
    const float* src = V + (size_t)b * NKK * DH;
    uint16_t* dst = Vf + (size_t)bid * 8192;
    #pragma unroll
    for (int r = 0; r < 4; ++r) {
        int c = r * 256 + tid;
        int s = c >> 6, lane = c & 63;
        int ci = s >> 3, nt = (s >> 1) & 3, uu = s & 1;
        int m = lane & 31, h = lane >> 5;
        int kb = kt * 64 + ci * 32 + uu * 16 + 4 * h;
        int d = nt * 32 + m;
        short8 w;
        #pragma unroll
        for (int j = 0; j < 8; ++j) {
            int key = kb + (j & 3) + 8 * (j >> 2);
            w[j] = (short)f2bf(src[(size_t)key * DH + d]);
        }
        *(short8*)(dst + (size_t)c * 8) = w;
    }
}

// ---------------- main attention: K via LDS, V register-prefetched from global ----------------
// 4 waves x 32 q, all 64 keys/tile. V-frags for tile kt+1 loaded to regs after PV of
// tile kt (one full iteration of latency cover). LDS read traffic halved vs r5.
__global__ __launch_bounds__(256, 2)
void attn_fwd(const float* __restrict__ Qg, const uint16_t* __restrict__ Kf,
              const uint16_t* __restrict__ Vf, const int* __restrict__ VL,
              float* __restrict__ Og) {
    __shared__ __align__(16) uint8_t LB[32768];  // K0|K1 (16KB each)

    const int tid  = threadIdx.x;
    const int wv   = tid >> 6;
    const int lane = tid & 63;
    const int m    = lane & 31;
    const int h    = lane >> 5;

    // bijective XCD swizzle: 512 blocks, 64 consecutive tiles (4 batches) per XCD
    const int bid = blockIdx.x;
    const int swz = (bid & 7) * 64 + (bid >> 3);
    const int b   = swz >> 4;
    const int qt  = swz & 15;
    const int qb0 = qt * QBLK + wv * 32;

    const int vlen = VL[b];
    const int qrow = qb0 + m;
    const float qsc = (qrow < vlen) ? C2 : 0.0f;   // scale+mask folded into Q (masked -> p=1)

    // Q fragments (B-operand of K.Q^T): qf[t] = C2 * Q[qb0+m][t*16+h*8+0..7]
    short8 qf[8];
    {
        const float* qp = Qg + ((size_t)b * NQ + qrow) * DH;
        #pragma unroll
        for (int t = 0; t < 8; ++t) {
            const float* p = qp + t * 16 + h * 8;
            f32x4 x0 = *(const f32x4*)(p);
            f32x4 x1 = *(const f32x4*)(p + 4);
            short8 f;
            f[0] = f2bf(x0[0] * qsc); f[1] = f2bf(x0[1] * qsc);
            f[2] = f2bf(x0[2] * qsc); f[3] = f2bf(x0[3] * qsc);
            f[4] = f2bf(x1[0] * qsc); f[5] = f2bf(x1[1] * qsc);
            f[6] = f2bf(x1[2] * qsc); f[7] = f2bf(x1[3] * qsc);
            qf[t] = f;
        }
    }

    f32x16 oacc[4];
    #pragma unroll
    for (int nt = 0; nt < 4; ++nt)
        #pragma unroll
        for (int r = 0; r < 16; ++r) oacc[nt][r] = 0.0f;
    float lsum = 0.0f;

    const char* kfb = (const char*)Kf + (size_t)b * 32 * 16384;
    const char* vfb = (const char*)Vf + (size_t)b * 32 * 16384;
    const char* vlanep = vfb + (size_t)lane * 16;

    auto stage = [&](int buf, int ktile) {   // K only: 4 global_load_lds per thread
        const char* ks = kfb + (size_t)ktile * 16384;
        char* kd = (char*)LB + buf * 16384;
        #pragma unroll
        for (int r = 0; r < 4; ++r)
            gload16(ks + r * 4096 + tid * 16, kd + r * 4096 + tid * 16);
    };

    short8 vreg[16];                          // V-frags of the CURRENT tile
    auto vload = [&](int ktile) {             // 16 coalesced dwordx4 per lane
        const char* vs = vlanep + (size_t)ktile * 16384;
        #pragma unroll
        for (int s = 0; s < 16; ++s)
            vreg[s] = *(const short8*)(vs + s * 1024);
    };

    stage(0, 0);
    vload(0);
    __syncthreads();

    int cur = 0;
    for (int kt = 0; kt < NKT; ++kt) {
        if (kt + 1 < NKT) stage(cur ^ 1, kt + 1);
        const char* KTc = (const char*)LB + cur * 16384 + (size_t)lane * 16;

        // ---- S^T[64 keys][32 q] = K . Q^T : lane-linear b128 LDS reads ----
        f32x16 sacc[2];
        #pragma unroll
        for (int ci = 0; ci < 2; ++ci)
            #pragma unroll
            for (int r = 0; r < 16; ++r) sacc[ci][r] = 0.0f;
        __builtin_amdgcn_s_setprio(1);
        #pragma unroll
        for (int t = 0; t < 8; ++t) {
            short8 kf0 = *(const short8*)(KTc + (0 * 8 + t) * 1024);
            short8 kf1 = *(const short8*)(KTc + (1 * 8 + t) * 1024);
            sacc[0] = __builtin_amdgcn_mfma_f32_32x32x16_bf16(kf0, qf[t], sacc[0], 0, 0, 0);
            sacc[1] = __builtin_amdgcn_mfma_f32_32x32x16_bf16(kf1, qf[t], sacc[1], 0, 0, 0);
        }
        __builtin_amdgcn_s_setprio(0);

        // ---- softmax (no max-sub; scale folded into Q) + lane-local P pack ----
        short8 pa[4];
        #pragma unroll
        for (int u = 0; u < 4; ++u) {
            const int ci = u >> 1;
            const int r0 = (u & 1) * 8;
            float p[8];
            #pragma unroll
            for (int j = 0; j < 8; ++j)
                p[j] = __builtin_amdgcn_exp2f(sacc[ci][r0 + j]);
            lsum += ((p[0] + p[1]) + (p[2] + p[3])) + ((p[4] + p[5]) + (p[6] + p[7]));
            union { uint32_t w[4]; short8 s; } pu;
            pu.w[0] = cvtpk(p[0], p[1]);
            pu.w[1] = cvtpk(p[2], p[3]);
            pu.w[2] = cvtpk(p[4], p[5]);
            pu.w[3] = cvtpk(p[6], p[7]);
            pa[u] = pu.s;
        }

        // ---- O += P . V : V-frags already in registers ----
        __builtin_amdgcn_s_setprio(1);
        #pragma unroll
        for (int nt = 0; nt < 4; ++nt) {
            #pragma unroll
            for (int u = 0; u < 4; ++u) {
                const int ci = u >> 1;
                const int uu = u & 1;
                oacc[nt] = __builtin_amdgcn_mfma_f32_32x32x16_bf16(pa[u], vreg[ci * 8 + nt * 2 + uu], oacc[nt], 0, 0, 0);
            }
        }
        __builtin_amdgcn_s_setprio(0);

        // ---- prefetch next tile's V into the just-consumed registers ----
        if (kt + 1 < NKT) vload(kt + 1);

        __syncthreads();
        cur ^= 1;
    }

    // ---- epilogue: divide by row-sum, write (r5 verbatim) ----
    float ltot = lsum + __shfl_xor(lsum, 32);
    float* op = Og + ((size_t)b * NQ + qb0) * DH;
    #pragma unroll
    for (int r = 0; r < 16; ++r) {
        const int qr = (r & 3) + 8 * (r >> 2) + 4 * h;
        float lv = __shfl(ltot, qr);
        float inv = 1.0f / lv;
        #pragma unroll
        for (int nt = 0; nt < 4; ++nt)
            op[(size_t)qr * DH + nt * 32 + m] = oacc[nt][r] * inv;
    }
}

extern "C" void kernel_launch(void* const* d_in, const int* in_sizes, int n_in,
                              void* d_out, int out_size, void* d_ws, size_t ws_size,
                              hipStream_t stream) {
    const float* q  = (const float*)d_in[0];
    const float* k  = (const float*)d_in[1];
    const float* v  = (const float*)d_in[2];
    const int*   vl = (const int*)d_in[3];
    float* out = (float*)d_out;

    uint16_t* Kf = (uint16_t*)d_ws;                         // 16 MB
    uint16_t* Vf = Kf + (size_t)NB * NKT * 8192;            // 16 MB

    conv_kf<<<NB * NKT, 256, 0, stream>>>(k, Kf);
    conv_vf<<<NB * NKT, 256, 0, stream>>>(v, Vf);
    attn_fwd<<<NB * (NQ / QBLK), 256, 0, stream>>>(q, Kf, Vf, vl, out);
}

// Round 14
// 97.437 us; speedup vs baseline: 1.0711x; 1.0711x over previous
//
#include <hip/hip_runtime.h>
#include <stdint.h>

#define NB 32
#define NQ 2048
#define NKK 2048
#define DH 128

constexpr int QBLK = 128;                   // 2 waves x 64 q
constexpr int KBLK = 64;
constexpr int NKT  = NKK / KBLK;            // 32
constexpr float C2 = 0.12754299817f;        // log2(e)/sqrt(128)

typedef short short8  __attribute__((ext_vector_type(8)));
typedef float f32x4   __attribute__((ext_vector_type(4)));
typedef float f32x16  __attribute__((ext_vector_type(16)));
typedef uint32_t u32x4 __attribute__((ext_vector_type(4)));

typedef __attribute__((address_space(3))) uint32_t lds_u32_t;
typedef __attribute__((address_space(1))) const uint32_t glb_u32_t;

__device__ __forceinline__ uint16_t f2bf(float x) {
    union { float f; uint32_t u; } v; v.f = x;
    uint32_t r = v.u + 0x7fffu + ((v.u >> 16) & 1u);   // RNE
    return (uint16_t)(r >> 16);
}

__device__ __forceinline__ void gload16(const void* g, void* l) {
    __builtin_amdgcn_global_load_lds((glb_u32_t*)g, (lds_u32_t*)l, 16, 0, 0);
}

__device__ __forceinline__ uint32_t cvtpk(float lo, float hi) {
    uint32_t d;
    asm("v_cvt_pk_bf16_f32 %0, %1, %2" : "=v"(d) : "v"(lo), "v"(hi));
    return d;
}

// ---------------- prep 1: K[b][k][d] fp32 -> Kf fragment stream (verbatim r5) ----------------
// Tile (b,kt) -> 16 segs x 64 lanes x 16B. Seg s = ci*8+t: lane l = (hh<<5)|mm holds
// bf16 K[kt*64 + ci*32 + mm][t*16 + hh*8 + 0..7]  (A-frag of mfma_32x32x16, keys=rows)
__global__ void conv_kf(const float* __restrict__ K, uint16_t* __restrict__ Kf) {
    __shared__ __align__(16) uint16_t T[64][136];
    const int bid = blockIdx.x;             // b*32 + kt
    const int b = bid >> 5, kt = bid & 31;
    const int tid = threadIdx.x;
    const float* src = K + ((size_t)(b * NKK + kt * 64)) * DH;
    #pragma unroll
    for (int r = 0; r < 8; ++r) {
        int flat = r * 256 + tid;           // 2048 f32x4 chunks
        int row = flat >> 5;
        int c4 = (flat & 31) * 4;
        f32x4 x = *(const f32x4*)(src + (size_t)row * DH + c4);
        T[row][c4 + 0] = f2bf(x[0]);
        T[row][c4 + 1] = f2bf(x[1]);
        T[row][c4 + 2] = f2bf(x[2]);
        T[row][c4 + 3] = f2bf(x[3]);
    }
    __syncthreads();
    uint16_t* dst = Kf + (size_t)bid * 8192;
    #pragma unroll
    for (int r = 0; r < 4; ++r) {
        int c = r * 256 + tid;              // chunk 0..1023
        int s = c >> 6, lane = c & 63;
        int ci = s >> 3, t = s & 7;
        int mm = lane & 31, hh = lane >> 5;
        short8 v = *(const short8*)&T[ci * 32 + mm][t * 16 + hh * 8];
        *(short8*)(dst + (size_t)c * 8) = v;
    }
}

// ---------------- prep 2: V[b][k][d] fp32 -> Vf fragment stream (verbatim r5) ----------------
// Seg s = ci*8 + nt*2 + uu: lane l=(h<<5)|m holds bf16
// V[kt*64 + ci*32 + uu*16 + 4h + (j&3)+8*(j>>2)][nt*32 + m], j=0..7  (B-frag of PV)
__global__ void conv_vf(const float* __restrict__ V, uint16_t* __restrict__ Vf) {
    const int bid = blockIdx.x;             // b*32 + kt
    const int b = bid >> 5, kt = bid & 31;
    const int tid = threadIdx.x;
    const float* src = V + (size_t)b * NKK * DH;
    uint16_t* dst = Vf + (size_t)bid * 8192;
    #pragma unroll
    for (int r = 0; r < 4; ++r) {
        int c = r * 256 + tid;
        int s = c >> 6, lane = c & 63;
        int ci = s >> 3, nt = (s >> 1) & 3, uu = s & 1;
        int m = lane & 31, h = lane >> 5;
        int kb = kt * 64 + ci * 32 + uu * 16 + 4 * h;
        int d = nt * 32 + m;
        short8 w;
        #pragma unroll
        for (int j = 0; j < 8; ++j) {
            int key = kb + (j & 3) + 8 * (j >> 2);
            w[j] = (short)f2bf(src[(size_t)key * DH + d]);
        }
        *(short8*)(dst + (size_t)c * 8) = w;
    }
}

// ---------------- main attention: 2-wave blocks, 64 q/wave, counted-vmcnt pipeline ----------------
// grid 512 -> 2 blocks/CU (independent barriers). Each frag read feeds 2 MFMAs
// (LDS bytes/MFMA halved vs r5). Staging loads stay in flight across raw barriers.
__global__ __launch_bounds__(128, 1)
void attn_fwd(const float* __restrict__ Qg, const uint16_t* __restrict__ Kf,
              const uint16_t* __restrict__ Vf, const int* __restrict__ VL,
              float* __restrict__ Og) {
    __shared__ __align__(16) uint8_t LB[65536];  // buf = K(16KB)|V(16KB), x2

    const int tid  = threadIdx.x;
    const int wv   = tid >> 6;
    const int lane = tid & 63;
    const int m    = lane & 31;
    const int h    = lane >> 5;

    // bijective XCD swizzle: 512 blocks, 64 consecutive tiles (4 batches) per XCD
    const int bid = blockIdx.x;
    const int swz = (bid & 7) * 64 + (bid >> 3);
    const int b   = swz >> 4;
    const int qt  = swz & 15;
    const int qb0 = qt * QBLK + wv * 64;

    const int vlen = VL[b];

    // Q fragments (B-operand of K.Q^T), pre-scaled by C2; masked rows -> 0 (=> p=1 uniform)
    short8 qf[2][8];
    #pragma unroll
    for (int qs = 0; qs < 2; ++qs) {
        const int qrow = qb0 + qs * 32 + m;
        const float qsc = (qrow < vlen) ? C2 : 0.0f;
        const float* qp = Qg + ((size_t)b * NQ + qrow) * DH;
        #pragma unroll
        for (int t = 0; t < 8; ++t) {
            const float* p = qp + t * 16 + h * 8;
            f32x4 x0 = *(const f32x4*)(p);
            f32x4 x1 = *(const f32x4*)(p + 4);
            short8 f;
            f[0] = f2bf(x0[0] * qsc); f[1] = f2bf(x0[1] * qsc);
            f[2] = f2bf(x0[2] * qsc); f[3] = f2bf(x0[3] * qsc);
            f[4] = f2bf(x1[0] * qsc); f[5] = f2bf(x1[1] * qsc);
            f[6] = f2bf(x1[2] * qsc); f[7] = f2bf(x1[3] * qsc);
            qf[qs][t] = f;
        }
    }

    f32x16 oacc[2][4];
    #pragma unroll
    for (int qs = 0; qs < 2; ++qs)
        #pragma unroll
        for (int nt = 0; nt < 4; ++nt)
            #pragma unroll
            for (int r = 0; r < 16; ++r) oacc[qs][nt][r] = 0.0f;
    float lsum[2] = {0.0f, 0.0f};

    const char* kfb = (const char*)Kf + (size_t)b * 32 * 16384;
    const char* vfb = (const char*)Vf + (size_t)b * 32 * 16384;

    auto stage = [&](int buf, int ktile) {   // 16 global_load_lds per thread
        const char* ks = kfb + (size_t)ktile * 16384;
        const char* vs = vfb + (size_t)ktile * 16384;
        char* kd = (char*)LB + buf * 32768;
        char* vd = kd + 16384;
        #pragma unroll
        for (int r = 0; r < 8; ++r) {
            gload16(ks + r * 2048 + tid * 16, kd + r * 2048 + tid * 16);
            gload16(vs + r * 2048 + tid * 16, vd + r * 2048 + tid * 16);
        }
    };

    stage(0, 0);
    asm volatile("s_waitcnt vmcnt(0)" ::: "memory");
    __builtin_amdgcn_s_barrier();
    __builtin_amdgcn_sched_barrier(0);

    int cur = 0;
    for (int kt = 0; kt < NKT; ++kt) {
        if (kt + 1 < NKT) {
            stage(cur ^ 1, kt + 1);                        // 16 newer loads in flight
            asm volatile("s_waitcnt vmcnt(16)" ::: "memory"); // tile kt's 16 loads done
        } else {
            asm volatile("s_waitcnt vmcnt(0)" ::: "memory");
        }
        __builtin_amdgcn_s_barrier();                      // all waves: tile kt in LDS
        __builtin_amdgcn_sched_barrier(0);

        const char* KTc = (const char*)LB + cur * 32768 + (size_t)lane * 16;
        const char* VTc = KTc + 16384;

        // ---- S^T: each K-frag feeds both qs ----
        short8 pa[2][4];
        #pragma unroll
        for (int ci = 0; ci < 2; ++ci) {
            f32x16 s0, s1;
            #pragma unroll
            for (int r = 0; r < 16; ++r) { s0[r] = 0.0f; s1[r] = 0.0f; }
            __builtin_amdgcn_s_setprio(1);
            #pragma unroll
            for (int t = 0; t < 8; ++t) {
                short8 kf = *(const short8*)(KTc + (ci * 8 + t) * 1024);
                s0 = __builtin_amdgcn_mfma_f32_32x32x16_bf16(kf, qf[0][t], s0, 0, 0, 0);
                s1 = __builtin_amdgcn_mfma_f32_32x32x16_bf16(kf, qf[1][t], s1, 0, 0, 0);
            }
            __builtin_amdgcn_s_setprio(0);
            // softmax (no max-sub; scale folded into Q) + lane-local P pack
            #pragma unroll
            for (int uu = 0; uu < 2; ++uu) {
                float p0[8], p1[8];
                #pragma unroll
                for (int j = 0; j < 8; ++j) {
                    p0[j] = __builtin_amdgcn_exp2f(s0[uu * 8 + j]);
                    p1[j] = __builtin_amdgcn_exp2f(s1[uu * 8 + j]);
                }
                lsum[0] += ((p0[0] + p0[1]) + (p0[2] + p0[3])) + ((p0[4] + p0[5]) + (p0[6] + p0[7]));
                lsum[1] += ((p1[0] + p1[1]) + (p1[2] + p1[3])) + ((p1[4] + p1[5]) + (p1[6] + p1[7]));
                union { uint32_t w[4]; short8 s; } u0, u1;
                u0.w[0] = cvtpk(p0[0], p0[1]); u0.w[1] = cvtpk(p0[2], p0[3]);
                u0.w[2] = cvtpk(p0[4], p0[5]); u0.w[3] = cvtpk(p0[6], p0[7]);
                u1.w[0] = cvtpk(p1[0], p1[1]); u1.w[1] = cvtpk(p1[2], p1[3]);
                u1.w[2] = cvtpk(p1[4], p1[5]); u1.w[3] = cvtpk(p1[6], p1[7]);
                pa[0][ci * 2 + uu] = u0.s;
                pa[1][ci * 2 + uu] = u1.s;
            }
        }

        // ---- O += P . V ; each V-frag feeds both qs ----
        __builtin_amdgcn_s_setprio(1);
        #pragma unroll
        for (int nt = 0; nt < 4; ++nt) {
            #pragma unroll
            for (int u = 0; u < 4; ++u) {
                const int ci = u >> 1;
                const int uu = u & 1;
                short8 vfr = *(const short8*)(VTc + (ci * 8 + nt * 2 + uu) * 1024);
                oacc[0][nt] = __builtin_amdgcn_mfma_f32_32x32x16_bf16(pa[0][u], vfr, oacc[0][nt], 0, 0, 0);
                oacc[1][nt] = __builtin_amdgcn_mfma_f32_32x32x16_bf16(pa[1][u], vfr, oacc[1][nt], 0, 0, 0);
            }
        }
        __builtin_amdgcn_s_setprio(0);

        __builtin_amdgcn_s_barrier();     // readers done before next stage overwrites
        __builtin_amdgcn_sched_barrier(0);
        cur ^= 1;
    }

    // ---- epilogue: divide by row-sum, write (r6 epilogue verbatim) ----
    float lt0 = lsum[0] + __shfl_xor(lsum[0], 32);
    float lt1 = lsum[1] + __shfl_xor(lsum[1], 32);
    float* op = Og + ((size_t)b * NQ + qb0) * DH;
    #pragma unroll
    for (int qs = 0; qs < 2; ++qs) {
        float ltq = qs ? lt1 : lt0;
        #pragma unroll
        for (int r = 0; r < 16; ++r) {
            const int qr = (r & 3) + 8 * (r >> 2) + 4 * h;
            float inv = 1.0f / __shfl(ltq, qr);
            #pragma unroll
            for (int nt = 0; nt < 4; ++nt)
                op[(size_t)(qs * 32 + qr) * DH + nt * 32 + m] = oacc[qs][nt][r] * inv;
        }
    }
}

extern "C" void kernel_launch(void* const* d_in, const int* in_sizes, int n_in,
                              void* d_out, int out_size, void* d_ws, size_t ws_size,
                              hipStream_t stream) {
    const float* q  = (const float*)d_in[0];
    const float* k  = (const float*)d_in[1];
    const float* v  = (const float*)d_in[2];
    const int*   vl = (const int*)d_in[3];
    float* out = (float*)d_out;

    uint16_t* Kf = (uint16_t*)d_ws;                         // 16 MB
    uint16_t* Vf = Kf + (size_t)NB * NKT * 8192;            // 16 MB

    conv_kf<<<NB * NKT, 256, 0, stream>>>(k, Kf);
    conv_vf<<<NB * NKT, 256, 0, stream>>>(v, Vf);
    attn_fwd<<<NB * (NQ / QBLK), 128, 0, stream>>>(q, Kf, Vf, vl, out);
}

// Round 15
// 86.734 us; speedup vs baseline: 1.2033x; 1.1234x over previous
//
#include <hip/hip_runtime.h>
#include <stdint.h>

#define NB 32
#define NQ 2048
#define NKK 2048
#define DH 128

constexpr int QBLK = 128;
constexpr int KBLK = 64;
constexpr int NKT  = NKK / KBLK;            // 32
constexpr float C2 = 0.12754299817f;        // log2(e)/sqrt(128)

typedef short short8  __attribute__((ext_vector_type(8)));
typedef float f32x4   __attribute__((ext_vector_type(4)));
typedef float f32x16  __attribute__((ext_vector_type(16)));
typedef uint32_t u32x4 __attribute__((ext_vector_type(4)));

typedef __attribute__((address_space(3))) uint32_t lds_u32_t;
typedef __attribute__((address_space(1))) const uint32_t glb_u32_t;

__device__ __forceinline__ uint16_t f2bf(float x) {
    union { float f; uint32_t u; } v; v.f = x;
    uint32_t r = v.u + 0x7fffu + ((v.u >> 16) & 1u);   // RNE
    return (uint16_t)(r >> 16);
}

__device__ __forceinline__ void gload16(const void* g, void* l) {
    __builtin_amdgcn_global_load_lds((glb_u32_t*)g, (lds_u32_t*)l, 16, 0, 0);
}

__device__ __forceinline__ uint32_t cvtpk(float lo, float hi) {
    uint32_t d;
    asm("v_cvt_pk_bf16_f32 %0, %1, %2" : "=v"(d) : "v"(lo), "v"(hi));
    return d;
}

// ---------------- fused prep: K and V fragment streams (bodies verbatim r5) ----------------
// Blocks [0,1024): K-path for tile bid. Blocks [1024,2048): V-path for tile bid-1024.
// Kf tile (b,kt): seg s=ci*8+t, lane (hh<<5)|mm = K[kt*64+ci*32+mm][t*16+hh*8+0..7]
// Vf tile (b,kt): seg s=ci*8+nt*2+uu, lane (h<<5)|m = V[kt*64+ci*32+uu*16+4h+(j&3)+8*(j>>2)][nt*32+m]
__global__ void conv_kv(const float* __restrict__ K, const float* __restrict__ V,
                        uint16_t* __restrict__ Kf, uint16_t* __restrict__ Vf) {
    __shared__ __align__(16) uint16_t T[64][136];
    const int bid0 = blockIdx.x;
    const int tid = threadIdx.x;
    if (bid0 < NB * NKT) {
        const int bid = bid0;
        const int b = bid >> 5, kt = bid & 31;
        const float* src = K + ((size_t)(b * NKK + kt * 64)) * DH;
        #pragma unroll
        for (int r = 0; r < 8; ++r) {
            int flat = r * 256 + tid;
            int row = flat >> 5;
            int c4 = (flat & 31) * 4;
            f32x4 x = *(const f32x4*)(src + (size_t)row * DH + c4);
            T[row][c4 + 0] = f2bf(x[0]);
            T[row][c4 + 1] = f2bf(x[1]);
            T[row][c4 + 2] = f2bf(x[2]);
            T[row][c4 + 3] = f2bf(x[3]);
        }
        __syncthreads();
        uint16_t* dst = Kf + (size_t)bid * 8192;
        #pragma unroll
        for (int r = 0; r < 4; ++r) {
            int c = r * 256 + tid;
            int s = c >> 6, lane = c & 63;
            int ci = s >> 3, t = s & 7;
            int mm = lane & 31, hh = lane >> 5;
            short8 v = *(const short8*)&T[ci * 32 + mm][t * 16 + hh * 8];
            *(short8*)(dst + (size_t)c * 8) = v;
        }
    } else {
        const int bid = bid0 - NB * NKT;
        const int b = bid >> 5, kt = bid & 31;
        const float* src = V + (size_t)b * NKK * DH;
        uint16_t* dst = Vf + (size_t)bid * 8192;
        #pragma unroll
        for (int r = 0; r < 4; ++r) {
            int c = r * 256 + tid;
            int s = c >> 6, lane = c & 63;
            int ci = s >> 3, nt = (s >> 1) & 3, uu = s & 1;
            int m = lane & 31, h = lane >> 5;
            int kb = kt * 64 + ci * 32 + uu * 16 + 4 * h;
            int d = nt * 32 + m;
            short8 w;
            #pragma unroll
            for (int j = 0; j < 8; ++j) {
                int key = kb + (j & 3) + 8 * (j >> 2);
                w[j] = (short)f2bf(src[(size_t)key * DH + d]);
            }
            *(short8*)(dst + (size_t)c * 8) = w;
        }
    }
}

// ---------------- main attention (r5 body; SINGLE barrier per K-tile) ----------------
// Loop: vmcnt(0) [own slice of tile kt landed] -> s_barrier [all slices landed AND all
// waves' reads of tile kt-1 consumed (MFMA operand order)] -> stage(kt+1) into the
// just-freed buffer -> compute kt. 32 barriers/block instead of 64.
__global__ __launch_bounds__(256, 2)
void attn_fwd(const float* __restrict__ Qg, const uint16_t* __restrict__ Kf,
              const uint16_t* __restrict__ Vf, const int* __restrict__ VL,
              float* __restrict__ Og) {
    __shared__ __align__(16) uint8_t LB[65536];  // K0|K1 (16KB each) | V0|V1 (16KB each)

    const int tid  = threadIdx.x;
    const int wv   = tid >> 6;
    const int lane = tid & 63;
    const int m    = lane & 31;
    const int h    = lane >> 5;

    // bijective XCD swizzle: 512 blocks, 64 consecutive tiles (4 batches) per XCD
    const int bid = blockIdx.x;
    const int swz = (bid & 7) * 64 + (bid >> 3);
    const int b   = swz >> 4;
    const int qt  = swz & 15;
    const int qb0 = qt * QBLK + wv * 32;

    const int vlen = VL[b];
    const int qrow = qb0 + m;
    const float qsc = (qrow < vlen) ? C2 : 0.0f;   // scale+mask folded into Q (masked -> p=1)

    // Q fragments (B-operand of K.Q^T): qf[t] = C2 * Q[qb0+m][t*16+h*8+0..7]
    short8 qf[8];
    {
        const float* qp = Qg + ((size_t)b * NQ + qrow) * DH;
        #pragma unroll
        for (int t = 0; t < 8; ++t) {
            const float* p = qp + t * 16 + h * 8;
            f32x4 x0 = *(const f32x4*)(p);
            f32x4 x1 = *(const f32x4*)(p + 4);
            short8 f;
            f[0] = f2bf(x0[0] * qsc); f[1] = f2bf(x0[1] * qsc);
            f[2] = f2bf(x0[2] * qsc); f[3] = f2bf(x0[3] * qsc);
            f[4] = f2bf(x1[0] * qsc); f[5] = f2bf(x1[1] * qsc);
            f[6] = f2bf(x1[2] * qsc); f[7] = f2bf(x1[3] * qsc);
            qf[t] = f;
        }
    }

    f32x16 oacc[4];
    #pragma unroll
    for (int nt = 0; nt < 4; ++nt)
        #pragma unroll
        for (int r = 0; r < 16; ++r) oacc[nt][r] = 0.0f;
    float lsum = 0.0f;

    const char* kfb = (const char*)Kf + (size_t)b * 32 * 16384;
    const char* vfb = (const char*)Vf + (size_t)b * 32 * 16384;

    auto stage = [&](int buf, int ktile) {   // 8 global_load_lds per thread
        const char* ks = kfb + (size_t)ktile * 16384;
        const char* vs = vfb + (size_t)ktile * 16384;
        char* kd = (char*)LB + buf * 16384;
        char* vd = (char*)LB + 32768 + buf * 16384;
        #pragma unroll
        for (int r = 0; r < 4; ++r) {
            gload16(ks + r * 4096 + tid * 16, kd + r * 4096 + tid * 16);
            gload16(vs + r * 4096 + tid * 16, vd + r * 4096 + tid * 16);
        }
    };

    stage(0, 0);

    for (int kt = 0; kt < NKT; ++kt) {
        const int cur = kt & 1;
        asm volatile("s_waitcnt vmcnt(0)" ::: "memory");   // own slice of tile kt landed
        __builtin_amdgcn_s_barrier();                      // tile kt ready; buf cur^1 free
        __builtin_amdgcn_sched_barrier(0);
        if (kt + 1 < NKT) stage(cur ^ 1, kt + 1);          // full compute phase to land

        const char* KTc = (const char*)LB + cur * 16384 + (size_t)lane * 16;
        const char* VTc = (const char*)LB + 32768 + cur * 16384 + (size_t)lane * 16;

        // ---- S^T[64 keys][32 q] = K . Q^T : lane-linear b128 reads ----
        f32x16 sacc[2];
        #pragma unroll
        for (int ci = 0; ci < 2; ++ci)
            #pragma unroll
            for (int r = 0; r < 16; ++r) sacc[ci][r] = 0.0f;
        __builtin_amdgcn_s_setprio(1);
        #pragma unroll
        for (int t = 0; t < 8; ++t) {
            short8 kf0 = *(const short8*)(KTc + (0 * 8 + t) * 1024);
            short8 kf1 = *(const short8*)(KTc + (1 * 8 + t) * 1024);
            sacc[0] = __builtin_amdgcn_mfma_f32_32x32x16_bf16(kf0, qf[t], sacc[0], 0, 0, 0);
            sacc[1] = __builtin_amdgcn_mfma_f32_32x32x16_bf16(kf1, qf[t], sacc[1], 0, 0, 0);
        }
        __builtin_amdgcn_s_setprio(0);

        // ---- softmax (no max-sub; scale folded into Q) + lane-local P pack ----
        short8 pa[4];
        #pragma unroll
        for (int u = 0; u < 4; ++u) {
            const int ci = u >> 1;
            const int r0 = (u & 1) * 8;
            float p[8];
            #pragma unroll
            for (int j = 0; j < 8; ++j)
                p[j] = __builtin_amdgcn_exp2f(sacc[ci][r0 + j]);
            lsum += ((p[0] + p[1]) + (p[2] + p[3])) + ((p[4] + p[5]) + (p[6] + p[7]));
            union { uint32_t w[4]; short8 s; } pu;
            pu.w[0] = cvtpk(p[0], p[1]);
            pu.w[1] = cvtpk(p[2], p[3]);
            pu.w[2] = cvtpk(p[4], p[5]);
            pu.w[3] = cvtpk(p[6], p[7]);
            pa[u] = pu.s;
        }

        // ---- O += P . V : lane-linear b128 reads ----
        __builtin_amdgcn_s_setprio(1);
        #pragma unroll
        for (int nt = 0; nt < 4; ++nt) {
            #pragma unroll
            for (int u = 0; u < 4; ++u) {
                const int ci = u >> 1;
                const int uu = u & 1;
                short8 vfr = *(const short8*)(VTc + (ci * 8 + nt * 2 + uu) * 1024);
                oacc[nt] = __builtin_amdgcn_mfma_f32_32x32x16_bf16(pa[u], vfr, oacc[nt], 0, 0, 0);
            }
        }
        __builtin_amdgcn_s_setprio(0);
    }

    // ---- epilogue: divide by row-sum, write (r5 verbatim) ----
    float ltot = lsum + __shfl_xor(lsum, 32);
    float* op = Og + ((size_t)b * NQ + qb0) * DH;
    #pragma unroll
    for (int r = 0; r < 16; ++r) {
        const int qr = (r & 3) + 8 * (r >> 2) + 4 * h;
        float lv = __shfl(ltot, qr);
        float inv = 1.0f / lv;
        #pragma unroll
        for (int nt = 0; nt < 4; ++nt)
            op[(size_t)qr * DH + nt * 32 + m] = oacc[nt][r] * inv;
    }
}

extern "C" void kernel_launch(void* const* d_in, const int* in_sizes, int n_in,
                              void* d_out, int out_size, void* d_ws, size_t ws_size,
                              hipStream_t stream) {
    const float* q  = (const float*)d_in[0];
    const float* k  = (const float*)d_in[1];
    const float* v  = (const float*)d_in[2];
    const int*   vl = (const int*)d_in[3];
    float* out = (float*)d_out;

    uint16_t* Kf = (uint16_t*)d_ws;                         // 16 MB
    uint16_t* Vf = Kf + (size_t)NB * NKT * 8192;            // 16 MB

    conv_kv<<<2 * NB * NKT, 256, 0, stream>>>(k, v, Kf, Vf);
    attn_fwd<<<NB * (NQ / QBLK), 256, 0, stream>>>(q, Kf, Vf, vl, out);
}